// Round 6
// baseline (175.338 us; speedup 1.0000x reference)
//
#include <hip/hip_runtime.h>
#include <math.h>

// Problem constants (fixed by the reference): N=2097152, G=8192, T=1000.
// N = 4 nodes/thread * 256 threads * 2048 blocks exactly.
#define GMAX 8192

typedef float nfloat4 __attribute__((ext_vector_type(4)));  // native vec for nontemporal

// Device-global scratch, fully rewritten every call (no cross-call state).
__device__ float g_coef[GMAX * 4];      // per-graph {c0,c1,cs,isf}
__device__ float g_sums[GMAX * 16];     // per-graph {Sx0[3],Sxt[3],M[9],count}
__device__ float g_gparams[GMAX * 16];  // per-graph: R[9], tvec[3], -,-,-,isf

// ---------------------------------------------------------------------------
// K0: blocks 0..7: redundant beta scan (T=1000, trivial) + per-graph coef
//     for g in [blk*1024, blk*1024+1024). blocks 8..39: zero g_sums.
// Removes the batch->tarr->g_sched dependent-load chain from hot kernels.
// ---------------------------------------------------------------------------
__global__ __launch_bounds__(1024) void k_prep(const float* __restrict__ beta,
                                               const int* __restrict__ tarr, int T) {
    int t = (int)threadIdx.x;
    if (blockIdx.x < 8) {
        __shared__ double sbeta[1024];
        __shared__ double buf[2][1024];
        double b = (t < T) ? (double)beta[t] : 0.0;
        sbeta[t] = b;
        buf[0][t] = b;
        __syncthreads();
        int src = 0;
        for (int off = 1; off < 1024; off <<= 1) {
            double v = buf[src][t];
            if (t >= off) v += buf[src][t - off];
            buf[src ^ 1][t] = v;
            src ^= 1;
            __syncthreads();
        }
        double total = buf[src][T - 1];
        int g = (int)blockIdx.x * 1024 + t;          // 0..8191
        int tg = tarr[g];
        double fwd2 = buf[src][tg];
        double bwd2 = total - fwd2 + sbeta[tg];
        double denom = fwd2 + bwd2;
        float4 cf;
        cf.x = (float)(fwd2 / denom);                // c0 (mu_x0)
        cf.y = (float)(bwd2 / denom);                // c1 (mu_x1)
        cf.z = (float)sqrt(fwd2 * bwd2 / denom);     // cs (std_sb)
        cf.w = (float)(1.0 / sqrt(fwd2));            // isf (1/std_fwd)
        ((float4*)g_coef)[g] = cf;
    } else {
        // 32 blocks * 1024 threads * float4 = 131072 floats = GMAX*16
        int i = ((int)blockIdx.x - 8) * 1024 + t;
        ((float4*)g_sums)[i] = make_float4(0.f, 0.f, 0.f, 0.f);
    }
}

__device__ inline void flush16(int g, const float* acc) {
    float* dst = &g_sums[g * 16];
    #pragma unroll
    for (int k = 0; k < 16; ++k) atomicAdd(dst + k, acc[k]);
}

// ---------------------------------------------------------------------------
// K1: 4 nodes/thread, fully coalesced float4 loads, ALL loads issued upfront
// (launch_bounds(256,4) -> 128 VGPR budget so they stay parallel in-flight).
// Compute x_t -> out; segmented wave suffix reduce; run-head lanes atomicAdd.
// ---------------------------------------------------------------------------
__global__ __launch_bounds__(256, 4) void k_accum(const float* __restrict__ x0,
                                                  const float* __restrict__ x1,
                                                  const float* __restrict__ noise,
                                                  const int* __restrict__ batch,
                                                  float* __restrict__ out_xt) {
    const int t = (int)blockIdx.x * 256 + (int)threadIdx.x;   // 0..524287
    const int4 gb = ((const int4*)batch)[t];

    const float4* X0 = (const float4*)x0;
    const float4* X1 = (const float4*)x1;
    const float4* XN = (const float4*)noise;
    // Issue all 9 independent loads together.
    float4 A0 = X0[3*t], A1 = X0[3*t+1], A2 = X0[3*t+2];
    float4 B0 = X1[3*t], B1 = X1[3*t+1], B2 = X1[3*t+2];
    float4 N0 = XN[3*t], N1 = XN[3*t+1], N2 = XN[3*t+2];

    const int gs[4] = {gb.x, gb.y, gb.z, gb.w};
    int gcur = gs[0];
    float4 cf = ((const float4*)g_coef)[gcur];      // one dependent load (L2-hot)

    float ax[12], bx[12], nx[12], tx[12];
    *(float4*)&ax[0] = A0; *(float4*)&ax[4] = A1; *(float4*)&ax[8] = A2;
    *(float4*)&bx[0] = B0; *(float4*)&bx[4] = B1; *(float4*)&bx[8] = B2;
    *(float4*)&nx[0] = N0; *(float4*)&nx[4] = N1; *(float4*)&nx[8] = N2;

    float acc[16];
    #pragma unroll
    for (int k = 0; k < 16; ++k) acc[k] = 0.0f;

    #pragma unroll
    for (int j = 0; j < 4; ++j) {
        if (gs[j] != gcur) {            // rare (~1.2% of threads)
            flush16(gcur, acc);
            #pragma unroll
            for (int k = 0; k < 16; ++k) acc[k] = 0.0f;
            gcur = gs[j];
            cf = ((const float4*)g_coef)[gcur];
        }
        float a0 = ax[3*j], a1 = ax[3*j+1], a2 = ax[3*j+2];
        float t0 = cf.x*a0 + cf.y*bx[3*j]   + cf.z*nx[3*j];
        float t1 = cf.x*a1 + cf.y*bx[3*j+1] + cf.z*nx[3*j+1];
        float t2 = cf.x*a2 + cf.y*bx[3*j+2] + cf.z*nx[3*j+2];
        tx[3*j] = t0; tx[3*j+1] = t1; tx[3*j+2] = t2;
        acc[0] += a0; acc[1] += a1; acc[2] += a2;
        acc[3] += t0; acc[4] += t1; acc[5] += t2;
        acc[6]  += a0*t0; acc[7]  += a0*t1; acc[8]  += a0*t2;
        acc[9]  += a1*t0; acc[10] += a1*t1; acc[11] += a1*t2;
        acc[12] += a2*t0; acc[13] += a2*t1; acc[14] += a2*t2;
        acc[15] += 1.0f;
    }

    float4* OUT = (float4*)out_xt;
    OUT[3*t]   = *(const float4*)&tx[0];
    OUT[3*t+1] = *(const float4*)&tx[4];
    OUT[3*t+2] = *(const float4*)&tx[8];

    // Wave segmented suffix reduce over (gcur, acc). g non-decreasing by lane.
    const int lane = (int)threadIdx.x & 63;
    #pragma unroll
    for (int off = 1; off < 64; off <<= 1) {
        int gq = __shfl_down(gcur, off, 64);
        bool valid = (lane + off < 64) && (gq == gcur);
        #pragma unroll
        for (int k = 0; k < 16; ++k) {
            float xq = __shfl_down(acc[k], off, 64);
            if (valid) acc[k] += xq;
        }
    }
    int gprev = __shfl_up(gcur, 1, 64);
    if (lane == 0 || gprev != gcur) flush16(gcur, acc);
}

// ---------------------------------------------------------------------------
// Kabsch from raw sums (double Jacobi on H^T H) — math validated R1-R3.
// Sweep cap 8, threshold 1e-24 (off-diag ~1e-12 rel; ample for f32 output).
// ---------------------------------------------------------------------------
__device__ void kabsch_store(const float* sum, int n, float isf, float* p) {
    double fn = (double)(n > 0 ? n : 1);
    double H[3][3];
    #pragma unroll
    for (int a = 0; a < 3; ++a)
        #pragma unroll
        for (int b = 0; b < 3; ++b)
            H[a][b] = (double)sum[6 + 3*a + b] - (double)sum[a] * (double)sum[3 + b] / fn;

    double A[3][3];
    #pragma unroll
    for (int i = 0; i < 3; ++i)
        #pragma unroll
        for (int j = 0; j < 3; ++j) {
            double acc = 0.0;
            #pragma unroll
            for (int k = 0; k < 3; ++k) acc += H[k][i] * H[k][j];
            A[i][j] = acc;
        }

    double V[3][3] = {{1,0,0},{0,1,0},{0,0,1}};
    for (int sweep = 0; sweep < 8; ++sweep) {
        double off = A[0][1]*A[0][1] + A[0][2]*A[0][2] + A[1][2]*A[1][2];
        double diag = A[0][0]*A[0][0] + A[1][1]*A[1][1] + A[2][2]*A[2][2];
        if (off <= 1e-24 * (diag + 1e-300)) break;
        for (int pi = 0; pi < 3; ++pi) {
            int P = (pi == 0) ? 0 : (pi == 1) ? 0 : 1;
            int Q = (pi == 0) ? 1 : (pi == 1) ? 2 : 2;
            double apq = A[P][Q];
            if (apq == 0.0) continue;
            double theta = (A[Q][Q] - A[P][P]) / (2.0 * apq);
            double tt = ((theta >= 0.0) ? 1.0 : -1.0) /
                        (fabs(theta) + sqrt(theta * theta + 1.0));
            double c = 1.0 / sqrt(tt * tt + 1.0);
            double s = tt * c;
            A[P][P] -= tt * apq;
            A[Q][Q] += tt * apq;
            A[P][Q] = A[Q][P] = 0.0;
            int Rr = 3 - P - Q;
            double arp = A[Rr][P], arq = A[Rr][Q];
            A[Rr][P] = A[P][Rr] = c * arp - s * arq;
            A[Rr][Q] = A[Q][Rr] = s * arp + c * arq;
            #pragma unroll
            for (int i = 0; i < 3; ++i) {
                double vip = V[i][P], viq = V[i][Q];
                V[i][P] = c * vip - s * viq;
                V[i][Q] = s * vip + c * viq;
            }
        }
    }
    double w[3] = {A[0][0], A[1][1], A[2][2]};
    int o0 = 0, o1 = 1, o2 = 2, tmp;
    if (w[o0] < w[o1]) { tmp = o0; o0 = o1; o1 = tmp; }
    if (w[o0] < w[o2]) { tmp = o0; o0 = o2; o2 = tmp; }
    if (w[o1] < w[o2]) { tmp = o1; o1 = o2; o2 = tmp; }

    double s0 = sqrt(fmax(w[o0], 0.0));
    double s1 = sqrt(fmax(w[o1], 0.0));
    double s2 = sqrt(fmax(w[o2], 0.0));
    double det = H[0][0]*(H[1][1]*H[2][2] - H[1][2]*H[2][1])
               - H[0][1]*(H[1][0]*H[2][2] - H[1][2]*H[2][0])
               + H[0][2]*(H[1][0]*H[2][1] - H[1][1]*H[2][0]);
    double d = (det >= 0.0) ? 1.0 : -1.0;
    double thr = 1e-9 * s0;
    double i0 = (s0 > 1e-300) ? 1.0 / s0 : 0.0;
    double i1 = (s1 > thr) ? 1.0 / s1 : 0.0;
    double i2 = (s2 > thr) ? d / s2 : 0.0;

    double B[3][3];
    #pragma unroll
    for (int i = 0; i < 3; ++i)
        #pragma unroll
        for (int j = 0; j < 3; ++j)
            B[i][j] = V[i][o0] * i0 * V[j][o0]
                    + V[i][o1] * i1 * V[j][o1]
                    + V[i][o2] * i2 * V[j][o2];

    double Rm[3][3];
    #pragma unroll
    for (int i = 0; i < 3; ++i)
        #pragma unroll
        for (int j = 0; j < 3; ++j)
            Rm[i][j] = B[i][0]*H[j][0] + B[i][1]*H[j][1] + B[i][2]*H[j][2];

    double com0[3], comt[3];
    #pragma unroll
    for (int a = 0; a < 3; ++a) { com0[a] = sum[a] / fn; comt[a] = sum[3+a] / fn; }

    #pragma unroll
    for (int i = 0; i < 3; ++i)
        #pragma unroll
        for (int j = 0; j < 3; ++j)
            p[3*i + j] = (float)Rm[i][j];
    #pragma unroll
    for (int i = 0; i < 3; ++i)
        p[9 + i] = (float)(comt[i] - (Rm[i][0]*com0[0] + Rm[i][1]*com0[1] + Rm[i][2]*com0[2]));
    p[12] = 0.f; p[13] = 0.f; p[14] = 0.f; p[15] = isf;
}

// ---------------------------------------------------------------------------
// K2: one thread per graph — Kabsch, fully parallel.
// ---------------------------------------------------------------------------
__global__ __launch_bounds__(256) void k_kabsch() {
    int g = (int)blockIdx.x * 256 + (int)threadIdx.x;
    if (g >= GMAX) return;
    float sum[16];
    #pragma unroll
    for (int q = 0; q < 4; ++q)
        *(float4*)&sum[4*q] = ((const float4*)&g_sums[g * 16])[q];
    float4 cf = ((const float4*)g_coef)[g];
    int n = (int)(sum[15] + 0.5f);
    kabsch_store(sum, n, cf.w, &g_gparams[g * 16]);
}

// ---------------------------------------------------------------------------
// K3: 4 nodes/thread, coalesced float4, upfront loads; params reloaded only
// on in-thread graph change. target = (x_t - (R x0 + tvec)) * isf.
// Nontemporal stores via native ext_vector_type (HIP float4 is a class and
// is rejected by __builtin_nontemporal_store).
// ---------------------------------------------------------------------------
__global__ __launch_bounds__(256, 4) void k_final(const float* __restrict__ x0,
                                                  const float* __restrict__ xt,
                                                  const int* __restrict__ batch,
                                                  float* __restrict__ out_tg) {
    const int t = (int)blockIdx.x * 256 + (int)threadIdx.x;
    const int4 gb = ((const int4*)batch)[t];

    const float4* XA = (const float4*)x0;
    const float4* XT = (const float4*)xt;
    float4 A0 = XA[3*t], A1 = XA[3*t+1], A2 = XA[3*t+2];
    float4 W0 = XT[3*t], W1 = XT[3*t+1], W2 = XT[3*t+2];

    const int gs[4] = {gb.x, gb.y, gb.z, gb.w};
    int gcur = gs[0];
    float pr[16];
    #pragma unroll
    for (int q = 0; q < 4; ++q)
        *(float4*)&pr[4*q] = ((const float4*)&g_gparams[gcur * 16])[q];

    float ax[12], wx[12], ox[12];
    *(float4*)&ax[0] = A0; *(float4*)&ax[4] = A1; *(float4*)&ax[8] = A2;
    *(float4*)&wx[0] = W0; *(float4*)&wx[4] = W1; *(float4*)&wx[8] = W2;

    #pragma unroll
    for (int j = 0; j < 4; ++j) {
        if (gs[j] != gcur) {
            gcur = gs[j];
            #pragma unroll
            for (int q = 0; q < 4; ++q)
                *(float4*)&pr[4*q] = ((const float4*)&g_gparams[gcur * 16])[q];
        }
        float a0 = ax[3*j], a1 = ax[3*j+1], a2 = ax[3*j+2];
        float al0 = pr[0]*a0 + pr[1]*a1 + pr[2]*a2 + pr[9];
        float al1 = pr[3]*a0 + pr[4]*a1 + pr[5]*a2 + pr[10];
        float al2 = pr[6]*a0 + pr[7]*a1 + pr[8]*a2 + pr[11];
        float isf = pr[15];
        ox[3*j]   = (wx[3*j]   - al0) * isf;
        ox[3*j+1] = (wx[3*j+1] - al1) * isf;
        ox[3*j+2] = (wx[3*j+2] - al2) * isf;
    }

    nfloat4* OUT = (nfloat4*)out_tg;
    __builtin_nontemporal_store(*(const nfloat4*)&ox[0], &OUT[3*t]);
    __builtin_nontemporal_store(*(const nfloat4*)&ox[4], &OUT[3*t+1]);
    __builtin_nontemporal_store(*(const nfloat4*)&ox[8], &OUT[3*t+2]);
}

extern "C" void kernel_launch(void* const* d_in, const int* in_sizes, int n_in,
                              void* d_out, int out_size, void* d_ws, size_t ws_size,
                              hipStream_t stream) {
    const float* x0    = (const float*)d_in[0];
    const float* x1    = (const float*)d_in[1];
    const float* noise = (const float*)d_in[2];
    const float* beta  = (const float*)d_in[3];
    const int*   batch = (const int*)d_in[4];
    const int*   tarr  = (const int*)d_in[5];

    int N = in_sizes[4];      // 2097152
    int T = in_sizes[3];      // 1000
    int nthreads = N / 4;     // 524288 -> 2048 blocks of 256

    float* out_xt = (float*)d_out;
    float* out_tg = out_xt + (size_t)3 * N;

    k_prep<<<40, 1024, 0, stream>>>(beta, tarr, T);
    k_accum<<<nthreads / 256, 256, 0, stream>>>(x0, x1, noise, batch, out_xt);
    k_kabsch<<<GMAX / 256, 256, 0, stream>>>();
    k_final<<<nthreads / 256, 256, 0, stream>>>(x0, out_xt, batch, out_tg);
}